// Round 12
// baseline (426.581 us; speedup 1.0000x reference)
//
#include <hip/hip_runtime.h>

#define NN 50000
#define NE 800000
#define NB 1563      // 32-row tiles (enc1/enc2): ceil(50000/32)
#define NBG 782      // enc grid: 2 tiles per block
#define NBM 3125     // 16-row tiles (mmega): ceil(50000/16)
#define NBMG 1042    // mmega grid: 3 tiles per block
#define TOTF 114688  // frag elems: W1 (8kc*4096=32768) + 5 matrices * 16384

typedef unsigned short u16;
typedef unsigned int u32;
typedef __attribute__((ext_vector_type(8))) short s8v;   // 8 bf16 = 4 VGPRs (MFMA A/B frag)
typedef __attribute__((ext_vector_type(4))) float f4v;   // MFMA C/D frag

// split fp32 into hi (truncated bf16) + lo (bf16 of remainder): f ~= hi + lo
__device__ __forceinline__ void split2(float f, u16& h, u16& lo) {
    u32 u = __float_as_uint(f);
    h = (u16)(u >> 16);
    float r = f - __uint_as_float(u & 0xFFFF0000u);   // exact
    lo = (u16)(__float_as_uint(r) >> 16);
}

// ---- prelude: weight frag prep + mask zero (scatter lives in enc1) ----
__global__ void prep_k(float* __restrict__ mask,
                       const float* __restrict__ W1, const float* __restrict__ W2,
                       const float* __restrict__ Wv, const float* __restrict__ Wo,
                       u16* __restrict__ fh, u16* __restrict__ fl) {
    int i = blockIdx.x * 256 + threadIdx.x;
    if (i < NN) mask[i] = 0.f;
    if (i < TOTF) {
        const float* W;
        int local;
        if (i < 32768) { W = W1; local = i; }
        else {
            int t = i - 32768;
            int m = t >> 14;
            local = t & 16383;
            if (m == 0) W = W2;
            else if (m == 1) W = Wv;
            else if (m == 2) W = Wo;
            else if (m == 3) W = Wv + 16384;
            else W = Wo + 16384;
        }
        int j = local & 7, l = (local >> 3) & 63, nt = (local >> 9) & 7, kc = local >> 12;
        int k = kc * 32 + ((l >> 4) << 3) + j;
        int n = nt * 16 + (l & 15);
        u16 h, lo;
        split2(W[k * 128 + n], h, lo);
        fh[i] = h;
        fl[i] = lo;
    }
}

// ---- reduce per-block stat partials: st[c] = sum_b pst[b][c] ----
__global__ __launch_bounds__(64)
void redstats_k(const float* __restrict__ pst, float* __restrict__ st) {
    int c = blockIdx.x;
    float s = 0.f;
    for (int b = threadIdx.x; b < NB; b += 64) s += pst[(size_t)b * 256 + c];
    s += __shfl_xor(s, 1);  s += __shfl_xor(s, 2);  s += __shfl_xor(s, 4);
    s += __shfl_xor(s, 8);  s += __shfl_xor(s, 16); s += __shfl_xor(s, 32);
    if (threadIdx.x == 0) st[c] = s;
}

// ---- MFMA GEMM, 32-row tiles, 4 waves (256 thr), 2 tiles/block (grid NBG) ----
// Cross-tile T14 prefetch: tile t+1 pass-0 loads issue under tile t's MFMA+epilogue,
// keeping global bytes in flight through otherwise load-idle phases; dispatch ramp
// and cold-start are paid once per 2 tiles.
template<int KC, int FOLD, int STATS, int SCAT>
__global__ __launch_bounds__(256, 8)
void mgemm_k(const float* __restrict__ A,
             const u16* __restrict__ fh, const u16* __restrict__ fl,
             const float* __restrict__ bias,
             const float* __restrict__ fst,        // prev-layer stats [256] (sum|sq)
             const float* __restrict__ fg, const float* __restrict__ fbe,
             const int* __restrict__ dstv,         // edge dst (SCAT only)
             float* __restrict__ maskw,            // mask out (SCAT only)
             float* __restrict__ pst,              // partials [NB][256] (tile-contiguous)
             float* __restrict__ C) {
    constexpr int KP = KC / 4;       // 128-wide K passes
    __shared__ __align__(16) u16 Ah[32][136];
    __shared__ __align__(16) u16 Al[32][136];
    __shared__ float scl[128], shf[128];
    const int tid = threadIdx.x;
    const int l = tid & 63, w = tid >> 6;        // 4 waves
    const int q = l >> 4, cc = l & 15;
    const int sl = w >> 1, hf = w & 1;           // slice 0..1, n-half 0..1
    const int lr = tid >> 5;                     // staging row base within group of 8
    const int c4 = (tid & 31) * 4;               // staged columns (const per thread)

    if (SCAT) {
        int e0 = (blockIdx.x * 256 + tid) * 4;   // 782*256*4 = 800768 >= NE
        if (e0 < NE) {                            // NE % 4 == 0
            int4 dd = *(const int4*)(dstv + e0);
            maskw[dd.x] = 1.0f;
            maskw[dd.y] = 1.0f;
            maskw[dd.z] = 1.0f;
            maskw[dd.w] = 1.0f;
        }
    }

    if (FOLD && tid < 128) {
        float mean = fst[tid] * (1.0f / NN);
        float var = fst[128 + tid] * (1.0f / NN) - mean * mean;   // biased
        float rstd = rsqrtf(var + 1e-5f);
        float ga = fg[tid] * rstd;
        scl[tid] = ga;
        shf[tid] = fbe[tid] - mean * ga;
    }

    f4v zf = {0.f, 0.f, 0.f, 0.f};

    // prefetch tile-0 pass-0
    float4 pref[4];
    {
        const int row0 = blockIdx.x * 64;        // tile 0 base
#pragma unroll
        for (int it = 0; it < 4; ++it) {
            int gr = row0 + lr + 8 * it; if (gr > NN - 1) gr = NN - 1;
            pref[it] = *(const float4*)(A + (size_t)gr * (KC * 32) + c4);
        }
    }

    for (int tt = 0; tt < 2; ++tt) {
        const int tile = blockIdx.x * 2 + tt;
        const int row0 = tile * 32;
        if (row0 >= NN) break;                   // skipped padding tile (id 1563)

        f4v acc[4];
#pragma unroll
        for (int t = 0; t < 4; ++t) acc[t] = zf;

        for (int p = 0; p < KP; ++p) {
            if (tt > 0 || p > 0 || FOLD) __syncthreads();  // LDS free for staging
#pragma unroll
            for (int it = 0; it < 4; ++it) {
                int r = lr + 8 * it;             // 0..31
                float v[4] = {pref[it].x, pref[it].y, pref[it].z, pref[it].w};
                if (FOLD) {
#pragma unroll
                    for (int m = 0; m < 4; ++m) {
                        float t = v[m] * scl[c4 + m] + shf[c4 + m];
                        v[m] = t > 0.f ? t : 0.f;
                    }
                }
                ushort4 uh, ul;
                split2(v[0], uh.x, ul.x); split2(v[1], uh.y, ul.y);
                split2(v[2], uh.z, ul.z); split2(v[3], uh.w, ul.w);
                *(ushort4*)&Ah[r][c4] = uh;
                *(ushort4*)&Al[r][c4] = ul;
            }
            __syncthreads();
            // prefetch next pass (same tile) or next tile's pass-0 under this MFMA phase
            if (p + 1 < KP) {
#pragma unroll
                for (int it = 0; it < 4; ++it) {
                    int gr = row0 + lr + 8 * it; if (gr > NN - 1) gr = NN - 1;
                    pref[it] = *(const float4*)(A + (size_t)gr * (KC * 32) + (p + 1) * 128 + c4);
                }
            } else if (tt == 0 && row0 + 32 < NN) {
#pragma unroll
                for (int it = 0; it < 4; ++it) {
                    int gr = row0 + 32 + lr + 8 * it; if (gr > NN - 1) gr = NN - 1;
                    pref[it] = *(const float4*)(A + (size_t)gr * (KC * 32) + c4);
                }
            }
#pragma unroll
            for (int kc = 0; kc < 4; ++kc) {
                int kcg = p * 4 + kc;
                s8v ah = *(const s8v*)&Ah[16 * sl + cc][kc * 32 + q * 8];
                s8v al = *(const s8v*)&Al[16 * sl + cc][kc * 32 + q * 8];
#pragma unroll
                for (int t = 0; t < 4; ++t) {
                    const int fo = kcg * 4096 + (4 * hf + t) * 512 + l * 8;
                    s8v bh = *(const s8v*)(fh + fo);
                    s8v bl = *(const s8v*)(fl + fo);
                    acc[t] = __builtin_amdgcn_mfma_f32_16x16x32_bf16(ah, bh, acc[t], 0, 0, 0);
                    acc[t] = __builtin_amdgcn_mfma_f32_16x16x32_bf16(ah, bl, acc[t], 0, 0, 0);
                    acc[t] = __builtin_amdgcn_mfma_f32_16x16x32_bf16(al, bh, acc[t], 0, 0, 0);
                }
            }
        }

        // epilogue: D[row=16sl+q*4+r][col=(4hf+t)*16+cc]; raw store + stat partials
        float ps[4], pq[4];
#pragma unroll
        for (int t = 0; t < 4; ++t) { ps[t] = 0.f; pq[t] = 0.f; }
#pragma unroll
        for (int t = 0; t < 4; ++t) {
            int col = (4 * hf + t) * 16 + cc;
            float bb = bias[col];
#pragma unroll
            for (int r = 0; r < 4; ++r) {
                int gr = row0 + 16 * sl + q * 4 + r;
                float val = acc[t][r] + bb;
                if (gr < NN) {
                    C[(size_t)gr * 128 + col] = val;
                    if (STATS) { ps[t] += val; pq[t] += val * val; }
                }
            }
        }
        if (STATS) {
            __syncthreads();                      // all LDS frag reads done: reuse Ah
            float* wredS = (float*)&Ah[0][0];     // [2][128]
            float* wredQ = wredS + 256;           // [2][128]
#pragma unroll
            for (int t = 0; t < 4; ++t) {
                ps[t] += __shfl_xor(ps[t], 16); ps[t] += __shfl_xor(ps[t], 32);
                pq[t] += __shfl_xor(pq[t], 16); pq[t] += __shfl_xor(pq[t], 32);
            }
            if (l < 16) {
#pragma unroll
                for (int t = 0; t < 4; ++t) {
                    int col = (4 * hf + t) * 16 + l;
                    wredS[sl * 128 + col] = ps[t];
                    wredQ[sl * 128 + col] = pq[t];
                }
            }
            __syncthreads();
            // tile-contiguous 1KB record: one coalesced burst per tile
            int c = tid & 127;
            const float* src = (tid < 128) ? wredS : wredQ;
            pst[(size_t)tile * 256 + tid] = src[c] + src[128 + c];
        }
    }
}

// ---- mega: bn2+relu -> (.@Wv0+bv0)*mask -> relu(.@Wo0+bo0) -> (.@Wv1+bv1)*mask
//            -> relu(.@Wo1+bo1) -> out.  16-row tiles, 2 waves, 3 tiles/block.
__global__ __launch_bounds__(128, 8)
void mmega_k(const float* __restrict__ X,
             const u16* __restrict__ fh, const u16* __restrict__ fl,   // Wv0 frag base
             const float* __restrict__ bv, const float* __restrict__ bo,
             const float* __restrict__ fst,
             const float* __restrict__ fg, const float* __restrict__ fbe,
             const float* __restrict__ mask, float* __restrict__ out) {
    __shared__ __align__(16) u16 Ah[16][136];
    __shared__ __align__(16) u16 Al[16][136];
    __shared__ float scl[128], shf[128];
    const int tid = threadIdx.x;
    const int l = tid & 63, w = tid >> 6;        // 2 waves
    const int q = l >> 4, cc = l & 15;
    const int hf = w;                            // n-half 0..1

    if (tid < 128) {
        float mean = fst[tid] * (1.0f / NN);
        float var = fst[128 + tid] * (1.0f / NN) - mean * mean;
        float rstd = rsqrtf(var + 1e-5f);
        float ga = fg[tid] * rstd;
        scl[tid] = ga;
        shf[tid] = fbe[tid] - mean * ga;
    }

    f4v zf = {0.f, 0.f, 0.f, 0.f};
    for (int tt = 0; tt < 3; ++tt) {
        const int tile = blockIdx.x * 3 + tt;
        const int row0 = tile * 16;
        if (row0 >= NN) break;                   // skipped padding tile (id 3125)
        __syncthreads();                         // prev tile's LDS reads done / scl ready

        float rm[4];
#pragma unroll
        for (int r = 0; r < 4; ++r) {
            int gr = row0 + q * 4 + r;
            rm[r] = (gr < NN) ? mask[gr] : 0.f;
        }

        // stage relu(bn2(X)) into split planes (cooperative, 16 rows x 128 k)
#pragma unroll
        for (int it = 0; it < 4; ++it) {
            int lin = tid + 128 * it;            // 0..511
            int r = lin >> 5;                    // 0..15
            int c4 = (lin & 31) * 4;
            int gr = row0 + r; if (gr > NN - 1) gr = NN - 1;
            float4 f = *(const float4*)(X + (size_t)gr * 128 + c4);
            float v[4] = {f.x, f.y, f.z, f.w};
            ushort4 uh, ul;
#pragma unroll
            for (int m = 0; m < 4; ++m) {
                float t = v[m] * scl[c4 + m] + shf[c4 + m];
                v[m] = t > 0.f ? t : 0.f;
            }
            split2(v[0], uh.x, ul.x); split2(v[1], uh.y, ul.y);
            split2(v[2], uh.z, ul.z); split2(v[3], uh.w, ul.w);
            *(ushort4*)&Ah[r][c4] = uh;
            *(ushort4*)&Al[r][c4] = ul;
        }
        __syncthreads();

        for (int s = 0; s < 4; ++s) {
            const u16* WH = fh + s * 16384;      // Wv0, Wo0, Wv1, Wo1 consecutive
            const u16* WL = fl + s * 16384;
            const float* bp = (s == 0) ? bv : (s == 1) ? bo : (s == 2) ? (bv + 128) : (bo + 128);

            f4v acc[4];
#pragma unroll
            for (int t = 0; t < 4; ++t) acc[t] = zf;
#pragma unroll
            for (int kc = 0; kc < 4; ++kc) {
                s8v ah = *(const s8v*)&Ah[cc][kc * 32 + q * 8];
                s8v al = *(const s8v*)&Al[cc][kc * 32 + q * 8];
#pragma unroll
                for (int t = 0; t < 4; ++t) {
                    const int fo = kc * 4096 + (4 * hf + t) * 512 + l * 8;
                    s8v bh = *(const s8v*)(WH + fo);
                    s8v bl = *(const s8v*)(WL + fo);
                    acc[t] = __builtin_amdgcn_mfma_f32_16x16x32_bf16(ah, bh, acc[t], 0, 0, 0);
                    acc[t] = __builtin_amdgcn_mfma_f32_16x16x32_bf16(ah, bl, acc[t], 0, 0, 0);
                    acc[t] = __builtin_amdgcn_mfma_f32_16x16x32_bf16(al, bh, acc[t], 0, 0, 0);
                }
            }

            if (s == 3) {
#pragma unroll
                for (int t = 0; t < 4; ++t) {
                    int col = (4 * hf + t) * 16 + cc;
                    float bb = bp[col];
#pragma unroll
                    for (int r = 0; r < 4; ++r) {
                        int gr = row0 + q * 4 + r;
                        if (gr < NN)
                            out[(size_t)gr * 128 + col] = fmaxf(acc[t][r] + bb, 0.f);
                    }
                }
            } else {
                __syncthreads();  // partner wave's reads done before overwrite
#pragma unroll
                for (int t = 0; t < 4; ++t) {
                    int col = (4 * hf + t) * 16 + cc;
                    float bb = bp[col];
#pragma unroll
                    for (int r = 0; r < 4; ++r) {
                        int rl = q * 4 + r;
                        float val = acc[t][r] + bb;
                        val = (s == 1) ? fmaxf(val, 0.f) : val * rm[r];
                        u16 h, lo; split2(val, h, lo);
                        Ah[rl][col] = h;
                        Al[rl][col] = lo;
                    }
                }
                __syncthreads();  // writes visible before next stage's reads
            }
        }
    }
}

extern "C" void kernel_launch(void* const* d_in, const int* in_sizes, int n_in,
                              void* d_out, int out_size, void* d_ws, size_t ws_size,
                              hipStream_t stream) {
    const float* x   = (const float*)d_in[0];
    const int*   ei  = (const int*)d_in[1];
    const float* W1  = (const float*)d_in[2];
    const float* b1  = (const float*)d_in[3];
    const float* g1  = (const float*)d_in[4];
    const float* be1 = (const float*)d_in[5];
    const float* W2  = (const float*)d_in[6];
    const float* b2  = (const float*)d_in[7];
    const float* g2  = (const float*)d_in[8];
    const float* be2 = (const float*)d_in[9];
    // Wq/bq (10,11), Wk/bk (12,13) cancel: V gathered at dst => segment softmax sums to 1.
    const float* Wv  = (const float*)d_in[14];
    const float* bv  = (const float*)d_in[15];
    const float* Wo  = (const float*)d_in[16];
    const float* bo  = (const float*)d_in[17];

    float* out = (float*)d_out;

    char* ws = (char*)d_ws;
    float* buf  = (float*)(ws);                    // 25.6 MB raw x@W1+b1
    float* mask = (float*)(ws + 25600000);         // 200 KB
    float* st1  = (float*)(ws + 25800704);         // 1 KB (sum|sq layer1)
    float* st2  = st1 + 256;                       // 1 KB (layer2)
    u16*   fH   = (u16*)(ws + 25804800);           // 229 KB frag hi
    u16*   fL   = fH + TOTF;                       // 229 KB frag lo
    float* pst  = (float*)(ws + 26263552);         // NB*256*4 = 1.6 MB partials (reused)

    // prelude: weight frags + mask zero (448 blocks)
    prep_k<<<dim3((TOTF + 255) / 256), dim3(256), 0, stream>>>(
        mask, W1, W2, Wv, Wo, fH, fL);

    dim3 gg(NBG), bb(256);
    // enc1: buf = x@W1+b1 (raw) + stat partials + fused edge->mask scatter
    mgemm_k<8, 0, 1, 1><<<gg, bb, 0, stream>>>(x, fH, fL, b1,
                                               nullptr, nullptr, nullptr,
                                               ei + NE, mask, pst, buf);
    redstats_k<<<dim3(256), dim3(64), 0, stream>>>(pst, st1);
    // enc2: out = relu(bn1(buf))@W2+b2 (raw) + stat partials
    mgemm_k<4, 1, 1, 0><<<gg, bb, 0, stream>>>(buf, fH + 32768, fL + 32768, b2,
                                               st1, g1, be1,
                                               nullptr, nullptr, pst, out);
    redstats_k<<<dim3(256), dim3(64), 0, stream>>>(pst, st2);
    // attention chain (collapsed), in-place on d_out, 3 tiles/block
    mmega_k<<<dim3(NBMG), dim3(128), 0, stream>>>(out, fH + 49152, fL + 49152, bv, bo,
                                                  st2, g2, be2, mask, out);
}

// Round 13
// 219.130 us; speedup vs baseline: 1.9467x; 1.9467x over previous
//
#include <hip/hip_runtime.h>

#define NN 50000
#define NE 800000
#define NB 1563      // ceil(NN/32) -- 32-row tiles (enc1/enc2)
#define NBM 3125     // NN/16 -- 16-row tiles (mmega)
#define TOTF 114688  // frag elems: W1 (8kc*4096=32768) + 5 matrices * 16384

typedef unsigned short u16;
typedef unsigned int u32;
typedef __attribute__((ext_vector_type(8))) short s8v;   // 8 bf16 = 4 VGPRs (MFMA A/B frag)
typedef __attribute__((ext_vector_type(4))) float f4v;   // MFMA C/D frag

// split fp32 into hi (truncated bf16) + lo (bf16 of remainder): f ~= hi + lo
__device__ __forceinline__ void split2(float f, u16& h, u16& lo) {
    u32 u = __float_as_uint(f);
    h = (u16)(u >> 16);
    float r = f - __uint_as_float(u & 0xFFFF0000u);   // exact
    lo = (u16)(__float_as_uint(r) >> 16);
}

// ---- prelude: weight frag prep + mask zero (scatter lives in enc1) ----
__global__ void prep_k(float* __restrict__ mask,
                       const float* __restrict__ W1, const float* __restrict__ W2,
                       const float* __restrict__ Wv, const float* __restrict__ Wo,
                       u16* __restrict__ fh, u16* __restrict__ fl) {
    int i = blockIdx.x * 256 + threadIdx.x;
    if (i < NN) mask[i] = 0.f;
    if (i < TOTF) {
        const float* W;
        int local;
        if (i < 32768) { W = W1; local = i; }
        else {
            int t = i - 32768;
            int m = t >> 14;
            local = t & 16383;
            if (m == 0) W = W2;
            else if (m == 1) W = Wv;
            else if (m == 2) W = Wo;
            else if (m == 3) W = Wv + 16384;
            else W = Wo + 16384;
        }
        int j = local & 7, l = (local >> 3) & 63, nt = (local >> 9) & 7, kc = local >> 12;
        int k = kc * 32 + ((l >> 4) << 3) + j;
        int n = nt * 16 + (l & 15);
        u16 h, lo;
        split2(W[k * 128 + n], h, lo);
        fh[i] = h;
        fl[i] = lo;
    }
}

// ---- reduce per-block stat partials: st[c] = sum_b pst[b][c] ----
__global__ __launch_bounds__(64)
void redstats_k(const float* __restrict__ pst, float* __restrict__ st) {
    int c = blockIdx.x;
    float s = 0.f;
    for (int b = threadIdx.x; b < NB; b += 64) s += pst[(size_t)b * 256 + c];
    s += __shfl_xor(s, 1);  s += __shfl_xor(s, 2);  s += __shfl_xor(s, 4);
    s += __shfl_xor(s, 8);  s += __shfl_xor(s, 16); s += __shfl_xor(s, 32);
    if (threadIdx.x == 0) st[c] = s;
}

// ---- MFMA GEMM, 32-row tiles, 4 waves (256 thr), 8 blocks/CU ----
// K in passes of 128 through a 32x136 split-bf16 LDS tile; register prefetch (T14).
// SCAT: fold the 800K-edge mask scatter in (mask is L2-resident; stores hide under MFMA).
template<int KC, int FOLD, int STATS, int SCAT>
__global__ __launch_bounds__(256, 8)
void mgemm_k(const float* __restrict__ A,
             const u16* __restrict__ fh, const u16* __restrict__ fl,
             const float* __restrict__ bias,
             const float* __restrict__ fst,        // prev-layer stats [256] (sum|sq)
             const float* __restrict__ fg, const float* __restrict__ fbe,
             const int* __restrict__ dstv,         // edge dst (SCAT only)
             float* __restrict__ maskw,            // mask out (SCAT only)
             float* __restrict__ pst,              // partials [NB][256] (block-contiguous)
             float* __restrict__ C) {
    constexpr int KP = KC / 4;       // 128-wide K passes
    __shared__ __align__(16) u16 Ah[32][136];
    __shared__ __align__(16) u16 Al[32][136];
    __shared__ float scl[128], shf[128];
    const int tid = threadIdx.x;
    const int l = tid & 63, w = tid >> 6;        // 4 waves
    const int q = l >> 4, cc = l & 15;
    const int sl = w >> 1, hf = w & 1;           // slice 0..1, n-half 0..1
    const int row0 = blockIdx.x * 32;

    if (SCAT) {
        int e2 = (blockIdx.x * 256 + tid) * 2;
        if (e2 + 1 < NE) {
            int2 dd = *(const int2*)(dstv + e2);
            maskw[dd.x] = 1.0f;
            maskw[dd.y] = 1.0f;
        }
    }

    if (FOLD && tid < 128) {
        float mean = fst[tid] * (1.0f / NN);
        float var = fst[128 + tid] * (1.0f / NN) - mean * mean;   // biased
        float rstd = rsqrtf(var + 1e-5f);
        float ga = fg[tid] * rstd;
        scl[tid] = ga;
        shf[tid] = fbe[tid] - mean * ga;
    }

    f4v zf = {0.f, 0.f, 0.f, 0.f};
    f4v acc[4];
#pragma unroll
    for (int t = 0; t < 4; ++t) acc[t] = zf;

    // T14: prefetch pass-p loads into regs; next pass issues right after staging sync
    float4 pref[4];
#pragma unroll
    for (int it = 0; it < 4; ++it) {
        int lin = tid + 256 * it;
        int r = lin >> 5;
        int c4 = (lin & 31) * 4;
        int gr = row0 + r; if (gr > NN - 1) gr = NN - 1;
        pref[it] = *(const float4*)(A + (size_t)gr * (KC * 32) + c4);
    }

    for (int p = 0; p < KP; ++p) {
        if (p > 0 || FOLD) __syncthreads();      // prev-pass reads done / scl ready
#pragma unroll
        for (int it = 0; it < 4; ++it) {
            int lin = tid + 256 * it;            // 0..1023
            int r = lin >> 5;                    // 0..31
            int c4 = (lin & 31) * 4;
            float v[4] = {pref[it].x, pref[it].y, pref[it].z, pref[it].w};
            if (FOLD) {
#pragma unroll
                for (int m = 0; m < 4; ++m) {
                    float t = v[m] * scl[c4 + m] + shf[c4 + m];
                    v[m] = t > 0.f ? t : 0.f;
                }
            }
            ushort4 uh, ul;
            split2(v[0], uh.x, ul.x); split2(v[1], uh.y, ul.y);
            split2(v[2], uh.z, ul.z); split2(v[3], uh.w, ul.w);
            *(ushort4*)&Ah[r][c4] = uh;
            *(ushort4*)&Al[r][c4] = ul;
        }
        __syncthreads();
        if (p + 1 < KP) {                        // issue next pass under MFMA phase
#pragma unroll
            for (int it = 0; it < 4; ++it) {
                int lin = tid + 256 * it;
                int r = lin >> 5;
                int c4 = (lin & 31) * 4;
                int gr = row0 + r; if (gr > NN - 1) gr = NN - 1;
                pref[it] = *(const float4*)(A + (size_t)gr * (KC * 32) + (p + 1) * 128 + c4);
            }
        }
#pragma unroll
        for (int kc = 0; kc < 4; ++kc) {
            int kcg = p * 4 + kc;
            s8v ah = *(const s8v*)&Ah[16 * sl + cc][kc * 32 + q * 8];
            s8v al = *(const s8v*)&Al[16 * sl + cc][kc * 32 + q * 8];
#pragma unroll
            for (int t = 0; t < 4; ++t) {
                const int fo = kcg * 4096 + (4 * hf + t) * 512 + l * 8;
                s8v bh = *(const s8v*)(fh + fo);
                s8v bl = *(const s8v*)(fl + fo);
                acc[t] = __builtin_amdgcn_mfma_f32_16x16x32_bf16(ah, bh, acc[t], 0, 0, 0);
                acc[t] = __builtin_amdgcn_mfma_f32_16x16x32_bf16(ah, bl, acc[t], 0, 0, 0);
                acc[t] = __builtin_amdgcn_mfma_f32_16x16x32_bf16(al, bh, acc[t], 0, 0, 0);
            }
        }
    }

    // epilogue: D[row=16sl+q*4+r][col=(4hf+t)*16+cc]; raw store + stat partials
    float ps[4], pq[4];
#pragma unroll
    for (int t = 0; t < 4; ++t) { ps[t] = 0.f; pq[t] = 0.f; }
#pragma unroll
    for (int t = 0; t < 4; ++t) {
        int col = (4 * hf + t) * 16 + cc;
        float bb = bias[col];
#pragma unroll
        for (int r = 0; r < 4; ++r) {
            int gr = row0 + 16 * sl + q * 4 + r;
            float val = acc[t][r] + bb;
            if (gr < NN) {
                C[(size_t)gr * 128 + col] = val;
                if (STATS) { ps[t] += val; pq[t] += val * val; }
            }
        }
    }
    if (STATS) {
        __syncthreads();                          // all LDS reads done: reuse Ah as wred
        float* wredS = (float*)&Ah[0][0];         // [2][128]
        float* wredQ = wredS + 256;               // [2][128]
#pragma unroll
        for (int t = 0; t < 4; ++t) {
            ps[t] += __shfl_xor(ps[t], 16); ps[t] += __shfl_xor(ps[t], 32);
            pq[t] += __shfl_xor(pq[t], 16); pq[t] += __shfl_xor(pq[t], 32);
        }
        if (l < 16) {
#pragma unroll
            for (int t = 0; t < 4; ++t) {
                int col = (4 * hf + t) * 16 + l;
                wredS[sl * 128 + col] = ps[t];
                wredQ[sl * 128 + col] = pq[t];
            }
        }
        __syncthreads();
        // block-contiguous 1KB record: one coalesced 64B-line-aligned burst per block
        int c = tid & 127;
        const float* src = (tid < 128) ? wredS : wredQ;
        pst[(size_t)blockIdx.x * 256 + tid] = src[c] + src[128 + c];
    }
}

// ---- mega: bn2+relu -> (.@Wv0+bv0)*mask -> relu(.@Wo0+bo0) -> (.@Wv1+bv1)*mask
//            -> relu(.@Wo1+bo1) -> out.  16-row tiles, 2 waves (round-6 config).
__global__ __launch_bounds__(128, 8)
void mmega_k(const float* __restrict__ X,
             const u16* __restrict__ fh, const u16* __restrict__ fl,   // Wv0 frag base
             const float* __restrict__ bv, const float* __restrict__ bo,
             const float* __restrict__ fst,
             const float* __restrict__ fg, const float* __restrict__ fbe,
             const float* __restrict__ mask, float* __restrict__ out) {
    __shared__ __align__(16) u16 Ah[16][136];
    __shared__ __align__(16) u16 Al[16][136];
    __shared__ float scl[128], shf[128];
    const int tid = threadIdx.x;
    const int l = tid & 63, w = tid >> 6;        // 2 waves
    const int q = l >> 4, cc = l & 15;
    const int hf = w;                            // n-half 0..1
    const int row0 = blockIdx.x * 16;

    if (tid < 128) {
        float mean = fst[tid] * (1.0f / NN);
        float var = fst[128 + tid] * (1.0f / NN) - mean * mean;
        float rstd = rsqrtf(var + 1e-5f);
        float ga = fg[tid] * rstd;
        scl[tid] = ga;
        shf[tid] = fbe[tid] - mean * ga;
    }
    __syncthreads();

    float rm[4];
#pragma unroll
    for (int r = 0; r < 4; ++r) {
        int gr = row0 + q * 4 + r;
        rm[r] = (gr < NN) ? mask[gr] : 0.f;
    }

    // stage relu(bn2(X)) into split planes (cooperative, 16 rows x 128 k)
#pragma unroll
    for (int it = 0; it < 4; ++it) {
        int lin = tid + 128 * it;                // 0..511
        int r = lin >> 5;                        // 0..15
        int c4 = (lin & 31) * 4;
        int gr = row0 + r; if (gr > NN - 1) gr = NN - 1;
        float4 f = *(const float4*)(X + (size_t)gr * 128 + c4);
        float v[4] = {f.x, f.y, f.z, f.w};
        ushort4 uh, ul;
#pragma unroll
        for (int m = 0; m < 4; ++m) {
            float t = v[m] * scl[c4 + m] + shf[c4 + m];
            v[m] = t > 0.f ? t : 0.f;
        }
        split2(v[0], uh.x, ul.x); split2(v[1], uh.y, ul.y);
        split2(v[2], uh.z, ul.z); split2(v[3], uh.w, ul.w);
        *(ushort4*)&Ah[r][c4] = uh;
        *(ushort4*)&Al[r][c4] = ul;
    }
    __syncthreads();

    f4v zf = {0.f, 0.f, 0.f, 0.f};
    for (int s = 0; s < 4; ++s) {
        const u16* WH = fh + s * 16384;     // Wv0, Wo0, Wv1, Wo1 consecutive
        const u16* WL = fl + s * 16384;
        const float* bp = (s == 0) ? bv : (s == 1) ? bo : (s == 2) ? (bv + 128) : (bo + 128);

        f4v acc[4];
#pragma unroll
        for (int t = 0; t < 4; ++t) acc[t] = zf;
#pragma unroll
        for (int kc = 0; kc < 4; ++kc) {
            s8v ah = *(const s8v*)&Ah[cc][kc * 32 + q * 8];
            s8v al = *(const s8v*)&Al[cc][kc * 32 + q * 8];
#pragma unroll
            for (int t = 0; t < 4; ++t) {
                const int fo = kc * 4096 + (4 * hf + t) * 512 + l * 8;
                s8v bh = *(const s8v*)(WH + fo);
                s8v bl = *(const s8v*)(WL + fo);
                acc[t] = __builtin_amdgcn_mfma_f32_16x16x32_bf16(ah, bh, acc[t], 0, 0, 0);
                acc[t] = __builtin_amdgcn_mfma_f32_16x16x32_bf16(ah, bl, acc[t], 0, 0, 0);
                acc[t] = __builtin_amdgcn_mfma_f32_16x16x32_bf16(al, bh, acc[t], 0, 0, 0);
            }
        }

        if (s == 3) {
#pragma unroll
            for (int t = 0; t < 4; ++t) {
                int col = (4 * hf + t) * 16 + cc;
                float bb = bp[col];
#pragma unroll
                for (int r = 0; r < 4; ++r) {
                    int gr = row0 + q * 4 + r;
                    if (gr < NN)
                        out[(size_t)gr * 128 + col] = fmaxf(acc[t][r] + bb, 0.f);
                }
            }
        } else {
            __syncthreads();    // partner wave's reads of this slice done before overwrite
#pragma unroll
            for (int t = 0; t < 4; ++t) {
                int col = (4 * hf + t) * 16 + cc;
                float bb = bp[col];
#pragma unroll
                for (int r = 0; r < 4; ++r) {
                    int rl = q * 4 + r;
                    float val = acc[t][r] + bb;
                    val = (s == 1) ? fmaxf(val, 0.f) : val * rm[r];
                    u16 h, lo; split2(val, h, lo);
                    Ah[rl][col] = h;
                    Al[rl][col] = lo;
                }
            }
            __syncthreads();    // writes visible before next stage's reads
        }
    }
}

extern "C" void kernel_launch(void* const* d_in, const int* in_sizes, int n_in,
                              void* d_out, int out_size, void* d_ws, size_t ws_size,
                              hipStream_t stream) {
    const float* x   = (const float*)d_in[0];
    const int*   ei  = (const int*)d_in[1];
    const float* W1  = (const float*)d_in[2];
    const float* b1  = (const float*)d_in[3];
    const float* g1  = (const float*)d_in[4];
    const float* be1 = (const float*)d_in[5];
    const float* W2  = (const float*)d_in[6];
    const float* b2  = (const float*)d_in[7];
    const float* g2  = (const float*)d_in[8];
    const float* be2 = (const float*)d_in[9];
    // Wq/bq (10,11), Wk/bk (12,13) cancel: V gathered at dst => segment softmax sums to 1.
    const float* Wv  = (const float*)d_in[14];
    const float* bv  = (const float*)d_in[15];
    const float* Wo  = (const float*)d_in[16];
    const float* bo  = (const float*)d_in[17];

    float* out = (float*)d_out;

    char* ws = (char*)d_ws;
    float* buf  = (float*)(ws);                    // 25.6 MB raw x@W1+b1
    float* mask = (float*)(ws + 25600000);         // 200 KB
    float* st1  = (float*)(ws + 25800704);         // 1 KB (sum|sq layer1)
    float* st2  = st1 + 256;                       // 1 KB (layer2)
    u16*   fH   = (u16*)(ws + 25804800);           // 229 KB frag hi
    u16*   fL   = fH + TOTF;                       // 229 KB frag lo
    float* pst  = (float*)(ws + 26263552);         // NB*256*4 = 1.6 MB partials (reused)

    // prelude: weight frags + mask zero (448 blocks; no memset, no scatter kernel)
    prep_k<<<dim3((TOTF + 255) / 256), dim3(256), 0, stream>>>(
        mask, W1, W2, Wv, Wo, fH, fL);

    dim3 gg(NB), bb(256);
    // enc1: buf = x@W1+b1 (raw) + stat partials + fused edge->mask scatter
    mgemm_k<8, 0, 1, 1><<<gg, bb, 0, stream>>>(x, fH, fL, b1,
                                               nullptr, nullptr, nullptr,
                                               ei + NE, mask, pst, buf);
    redstats_k<<<dim3(256), dim3(64), 0, stream>>>(pst, st1);
    // enc2: out = relu(bn1(buf))@W2+b2 (raw) + stat partials
    mgemm_k<4, 1, 1, 0><<<gg, bb, 0, stream>>>(buf, fH + 32768, fL + 32768, b2,
                                               st1, g1, be1,
                                               nullptr, nullptr, pst, out);
    redstats_k<<<dim3(256), dim3(64), 0, stream>>>(pst, st2);
    // attention chain (collapsed), in-place on d_out, 16-row tiles
    mmega_k<<<dim3(NBM), dim3(128), 0, stream>>>(out, fH + 49152, fL + 49152, bv, bo,
                                                 st2, g2, be2, mask, out);
}